// Round 1
// baseline (616.013 us; speedup 1.0000x reference)
//
#include <hip/hip_runtime.h>
#include <hip/hip_bf16.h>
#include <cstdint>

#define S_SEQ   2048
#define HID     4096
#define NQH     32
#define NKVH    8
#define DH      128
#define QKV_LD  6144      // (32+16)*128
#define SCALE_F 0.08838834764831845f

using f32x4  = __attribute__((ext_vector_type(4))) float;
using bf16x8 = __attribute__((ext_vector_type(8))) __bf16;

#define GLOAD_LDS16(gp, lp)                                                   \
  __builtin_amdgcn_global_load_lds(                                           \
      (__attribute__((address_space(1))) const void*)(gp),                    \
      (__attribute__((address_space(3))) void*)(lp), 16, 0, 0)

__device__ __forceinline__ unsigned short f2bf_bits(float f) {
  __hip_bfloat16 b = __float2bfloat16(f);
  return __builtin_bit_cast(unsigned short, b);
}

// ---------------------------------------------------------------------------
// f32 -> bf16 conversion (vectorized, grid-stride)
// ---------------------------------------------------------------------------
__global__ void cvt_f32_bf16(const float* __restrict__ in,
                             __hip_bfloat16* __restrict__ out, int n) {
  int i = blockIdx.x * blockDim.x + threadIdx.x;
  int stride = gridDim.x * blockDim.x;
  for (int e = i * 4; e < n; e += stride * 4) {
    float4 v = *(const float4*)(in + e);
    ushort4 u;
    u.x = f2bf_bits(v.x); u.y = f2bf_bits(v.y);
    u.z = f2bf_bits(v.z); u.w = f2bf_bits(v.w);
    *reinterpret_cast<ushort4*>(reinterpret_cast<unsigned short*>(out) + e) = u;
  }
}

// ---------------------------------------------------------------------------
// GEMM: C[M,N] = A[M,K] * B[N,K]^T   (both bf16, B^T layout)
// m97 structure: 128x128 tile, BK=32, 4 waves (2x2), global_load_lds staging.
// ---------------------------------------------------------------------------
template <bool OUT_BF16>
__global__ __launch_bounds__(256) void gemm_bt_kernel(
    const __hip_bfloat16* __restrict__ A, const __hip_bfloat16* __restrict__ B,
    void* __restrict__ Cv, int M, int N, int K) {
  __shared__ __hip_bfloat16 sA[128 * 32];
  __shared__ __hip_bfloat16 sB[128 * 32];
  const int tid = threadIdx.x;
  const int w = tid >> 6, l = tid & 63;
  const int wr = w >> 1, wc = w & 1;
  const int lr = l & 15, lk = (l >> 4) << 3;
  const int brow = blockIdx.y * 128;
  const int bcol = blockIdx.x * 128;

  f32x4 acc[4][4];
#pragma unroll
  for (int m = 0; m < 4; m++)
#pragma unroll
    for (int n = 0; n < 4; n++) acc[m][n] = (f32x4){0.f, 0.f, 0.f, 0.f};

  const int r0 = tid >> 2;         // 0..63
  const int c0 = (tid & 3) << 3;   // 0,8,16,24
  const __hip_bfloat16* Ag = A + (size_t)(brow + r0) * K + c0;
  const __hip_bfloat16* Bg = B + (size_t)(bcol + r0) * K + c0;

  for (int k0 = 0; k0 < K; k0 += 32) {
    GLOAD_LDS16(Ag + k0,                  sA + tid * 8);
    GLOAD_LDS16(Ag + k0 + (size_t)64 * K, sA + 2048 + tid * 8);
    GLOAD_LDS16(Bg + k0,                  sB + tid * 8);
    GLOAD_LDS16(Bg + k0 + (size_t)64 * K, sB + 2048 + tid * 8);
    __syncthreads();

    bf16x8 af[4], bfr[4];
#pragma unroll
    for (int m = 0; m < 4; m++)
      af[m] = *(const bf16x8*)&sA[(wr * 64 + m * 16 + lr) * 32 + lk];
#pragma unroll
    for (int n = 0; n < 4; n++)
      bfr[n] = *(const bf16x8*)&sB[(wc * 64 + n * 16 + lr) * 32 + lk];
#pragma unroll
    for (int m = 0; m < 4; m++)
#pragma unroll
      for (int n = 0; n < 4; n++)
        acc[m][n] = __builtin_amdgcn_mfma_f32_16x16x32_bf16(af[m], bfr[n],
                                                            acc[m][n], 0, 0, 0);
    __syncthreads();
  }

  const int jr = (l >> 4) << 2;  // C/D row base: row = (lane>>4)*4 + reg
  if (OUT_BF16) {
    __hip_bfloat16* C = (__hip_bfloat16*)Cv;
#pragma unroll
    for (int m = 0; m < 4; m++)
#pragma unroll
      for (int n = 0; n < 4; n++)
#pragma unroll
        for (int j = 0; j < 4; j++) {
          size_t row = brow + wr * 64 + m * 16 + jr + j;
          size_t col = bcol + wc * 64 + n * 16 + lr;
          C[row * N + col] = __float2bfloat16(acc[m][n][j]);
        }
  } else {
    float* C = (float*)Cv;
#pragma unroll
    for (int m = 0; m < 4; m++)
#pragma unroll
      for (int n = 0; n < 4; n++)
#pragma unroll
        for (int j = 0; j < 4; j++) {
          size_t row = brow + wr * 64 + m * 16 + jr + j;
          size_t col = bcol + wc * 64 + n * 16 + lr;
          C[row * N + col] = acc[m][n][j];
        }
  }
}

// ---------------------------------------------------------------------------
// RoPE (neox) applied in-place to Q (heads 0..31) and K (heads 32..39) of QKV.
// One thread per (s, head, d<64) pair.
// ---------------------------------------------------------------------------
__global__ void rope_kernel(__hip_bfloat16* __restrict__ QKV,
                            const int* __restrict__ pos) {
  int idx = blockIdx.x * blockDim.x + threadIdx.x;  // S*40*64 total
  int d = idx & 63;
  int head = (idx >> 6) % 40;
  int s = idx / (64 * 40);
  float p = (float)pos[s];
  // inv_freq = 10000^(-d/64) = 2^(-d * log2(10000)/64)
  float inv = exp2f(-(float)d * 0.2076205059304297f);
  float fr = p * inv;
  float sn, cs;
  sincosf(fr, &sn, &cs);
  size_t base = (size_t)s * QKV_LD + head * 128 + d;
  float x1 = __bfloat162float(QKV[base]);
  float x2 = __bfloat162float(QKV[base + 64]);
  QKV[base]      = __float2bfloat16(x1 * cs - x2 * sn);
  QKV[base + 64] = __float2bfloat16(x2 * cs + x1 * sn);
}

// ---------------------------------------------------------------------------
// V transpose: Vt[kvh][d][s] = QKV[s][5120 + kvh*128 + d]
// ---------------------------------------------------------------------------
__global__ void vtrans_kernel(const __hip_bfloat16* __restrict__ QKV,
                              __hip_bfloat16* __restrict__ Vt) {
  int idx = blockIdx.x * blockDim.x + threadIdx.x;  // 8*128*2048
  int s = idx & 2047;
  int d = (idx >> 11) & 127;
  int kh = idx >> 18;
  Vt[idx] = QKV[(size_t)s * QKV_LD + 5120 + kh * 128 + d];
}

// ---------------------------------------------------------------------------
// Causal GQA flash attention.
// Block = (head h, q-tile of 64 rows). 4 waves x 16 rows. KBLK=32.
// Q,K read from QKV (post-RoPE); V read from Vt (transposed); out bf16.
// ---------------------------------------------------------------------------
__global__ __launch_bounds__(256) void attn_kernel(
    const __hip_bfloat16* __restrict__ QKV,
    const __hip_bfloat16* __restrict__ Vt, __hip_bfloat16* __restrict__ O) {
  __shared__ __hip_bfloat16 Ps[4][16][32];  // per-wave P tile
  const int tid = threadIdx.x;
  const int w = tid >> 6, l = tid & 63;
  const int h = blockIdx.x;    // q head
  const int qt = blockIdx.y;   // q tile (64 rows)
  const int kvh = h >> 2;      // G = 4
  const int qb = qt * 64 + w * 16;  // this wave's q base row
  const int lr = l & 15;
  const int lk = (l >> 4) << 3;
  const int jr = (l >> 4) << 2;  // D-layout row base

  const __hip_bfloat16* Qp = QKV + (size_t)h * DH;
  const __hip_bfloat16* Kp = QKV + 4096 + (size_t)kvh * DH;
  const __hip_bfloat16* Vp = Vt + (size_t)kvh * (DH * S_SEQ);

  // preload Q fragments for this wave's 16 rows (A-operand: row = lane&15)
  bf16x8 qf[4];
  {
    const __hip_bfloat16* qrow = Qp + (size_t)(qb + lr) * QKV_LD + lk;
#pragma unroll
    for (int kk = 0; kk < 4; kk++) qf[kk] = *(const bf16x8*)(qrow + kk * 32);
  }

  f32x4 oacc[8];
#pragma unroll
  for (int dc = 0; dc < 8; dc++) oacc[dc] = (f32x4){0.f, 0.f, 0.f, 0.f};
  float mrun[4], lrun[4];
#pragma unroll
  for (int j = 0; j < 4; j++) { mrun[j] = -1e30f; lrun[j] = 0.f; }

  const int nt = (qb >> 5) + 1;  // causal per-wave trip count
  for (int t = 0; t < nt; t++) {
    const int kb = t << 5;
    f32x4 sacc[2];
    sacc[0] = (f32x4){0.f, 0.f, 0.f, 0.f};
    sacc[1] = (f32x4){0.f, 0.f, 0.f, 0.f};
#pragma unroll
    for (int n = 0; n < 2; n++) {
      const __hip_bfloat16* kr = Kp + (size_t)(kb + n * 16 + lr) * QKV_LD + lk;
#pragma unroll
      for (int kk = 0; kk < 4; kk++) {
        bf16x8 kf = *(const bf16x8*)(kr + kk * 32);
        sacc[n] =
            __builtin_amdgcn_mfma_f32_16x16x32_bf16(qf[kk], kf, sacc[n], 0, 0, 0);
      }
    }
    // online softmax per row (rows jr..jr+3 of this lane group)
#pragma unroll
    for (int j = 0; j < 4; j++) {
      const int q = qb + jr + j;
      float s0 = (kb + lr <= q) ? sacc[0][j] * SCALE_F : -1e30f;
      float s1 = (kb + 16 + lr <= q) ? sacc[1][j] * SCALE_F : -1e30f;
      float rm = fmaxf(s0, s1);
      rm = fmaxf(rm, __shfl_xor(rm, 1));
      rm = fmaxf(rm, __shfl_xor(rm, 2));
      rm = fmaxf(rm, __shfl_xor(rm, 4));
      rm = fmaxf(rm, __shfl_xor(rm, 8));
      float mn = fmaxf(mrun[j], rm);
      float sc = __expf(mrun[j] - mn);
      float p0 = __expf(s0 - mn);
      float p1 = __expf(s1 - mn);
      float rs = p0 + p1;
      rs += __shfl_xor(rs, 1);
      rs += __shfl_xor(rs, 2);
      rs += __shfl_xor(rs, 4);
      rs += __shfl_xor(rs, 8);
      lrun[j] = lrun[j] * sc + rs;
      mrun[j] = mn;
#pragma unroll
      for (int dc = 0; dc < 8; dc++) oacc[dc][j] *= sc;
      Ps[w][jr + j][lr] = __float2bfloat16(p0);
      Ps[w][jr + j][lr + 16] = __float2bfloat16(p1);
    }
    // wave-internal LDS ordering (no cross-wave sharing -> no barrier)
    asm volatile("s_waitcnt lgkmcnt(0)" ::: "memory");
    bf16x8 pa = *(const bf16x8*)&Ps[w][lr][lk];
#pragma unroll
    for (int dc = 0; dc < 8; dc++) {
      bf16x8 vf = *(const bf16x8*)(Vp + (size_t)(dc * 16 + lr) * S_SEQ + kb + lk);
      oacc[dc] = __builtin_amdgcn_mfma_f32_16x16x32_bf16(pa, vf, oacc[dc], 0, 0, 0);
    }
  }

#pragma unroll
  for (int j = 0; j < 4; j++) {
    float inv = 1.0f / lrun[j];
    const size_t rowoff = (size_t)(qb + jr + j) * (NQH * DH) + h * DH;
#pragma unroll
    for (int dc = 0; dc < 8; dc++)
      O[rowoff + dc * 16 + lr] = __float2bfloat16(oacc[dc][j] * inv);
  }
}

// ---------------------------------------------------------------------------
extern "C" void kernel_launch(void* const* d_in, const int* in_sizes, int n_in,
                              void* d_out, int out_size, void* d_ws,
                              size_t ws_size, hipStream_t stream) {
  const float* hs = (const float*)d_in[0];
  const int* pos = (const int*)d_in[1];
  const float* wqkv = (const float*)d_in[2];
  const float* wo = (const float*)d_in[3];
  float* out = (float*)d_out;

  char* ws = (char*)d_ws;
  __hip_bfloat16* Xb      = (__hip_bfloat16*)(ws);                // 16 MB
  __hip_bfloat16* Wqkvb   = (__hip_bfloat16*)(ws + 16777216);     // 48 MB
  __hip_bfloat16* Wob     = (__hip_bfloat16*)(ws + 67108864);     // 32 MB
  __hip_bfloat16* QKV     = (__hip_bfloat16*)(ws + 100663296);    // 24 MB
  __hip_bfloat16* AttnOut = (__hip_bfloat16*)(ws + 125829120);    // 16 MB
  __hip_bfloat16* Vt      = (__hip_bfloat16*)(ws + 142606336);    // 4 MB

  cvt_f32_bf16<<<2048, 256, 0, stream>>>(hs, Xb, S_SEQ * HID);
  cvt_f32_bf16<<<2048, 256, 0, stream>>>(wqkv, Wqkvb, QKV_LD * HID);
  cvt_f32_bf16<<<2048, 256, 0, stream>>>(wo, Wob, HID * HID);

  gemm_bt_kernel<true><<<dim3(QKV_LD / 128, S_SEQ / 128), 256, 0, stream>>>(
      Xb, Wqkvb, QKV, S_SEQ, QKV_LD, HID);

  rope_kernel<<<(S_SEQ * 40 * 64) / 256, 256, 0, stream>>>(QKV, pos);
  vtrans_kernel<<<(NKVH * DH * S_SEQ) / 256, 256, 0, stream>>>(QKV, Vt);

  attn_kernel<<<dim3(NQH, S_SEQ / 64), 256, 0, stream>>>(QKV, Vt, AttnOut);

  gemm_bt_kernel<false><<<dim3(HID / 128, S_SEQ / 128), 256, 0, stream>>>(
      AttnOut, Wob, out, S_SEQ, HID, HID);
}

// Round 2
// 592.887 us; speedup vs baseline: 1.0390x; 1.0390x over previous
//
#include <hip/hip_runtime.h>
#include <hip/hip_bf16.h>
#include <cstdint>

#define S_SEQ   2048
#define HID     4096
#define NQH     32
#define NKVH    8
#define DH      128
#define QKV_LD  6144      // (32+16)*128
#define SCALE_F 0.08838834764831845f
// softmax in log2 domain: s' = s * SCALE * log2(e)
#define C2F (0.08838834764831845f * 1.4426950408889634f)

using f32x4  = __attribute__((ext_vector_type(4))) float;
using bf16x8 = __attribute__((ext_vector_type(8))) __bf16;

#define GLOAD_LDS16(gp, lp)                                                   \
  __builtin_amdgcn_global_load_lds(                                           \
      (__attribute__((address_space(1))) const void*)(gp),                    \
      (__attribute__((address_space(3))) void*)(lp), 16, 0, 0)

__device__ __forceinline__ unsigned short f2bf_bits(float f) {
  __hip_bfloat16 b = __float2bfloat16(f);
  return __builtin_bit_cast(unsigned short, b);
}

// ---- DPP 16-lane-row reductions (VALU pipe, no DS traffic) -----------------
template <int CTRL>
__device__ __forceinline__ float dppf(float x) {
  return __builtin_bit_cast(
      float, __builtin_amdgcn_update_dpp(__builtin_bit_cast(int, x),
                                         __builtin_bit_cast(int, x), CTRL, 0xF,
                                         0xF, false));
}
__device__ __forceinline__ float row16_max(float x) {
  x = fmaxf(x, dppf<0x128>(x));  // row_ror:8
  x = fmaxf(x, dppf<0x124>(x));  // row_ror:4
  x = fmaxf(x, dppf<0x122>(x));  // row_ror:2
  x = fmaxf(x, dppf<0x121>(x));  // row_ror:1
  return x;
}
__device__ __forceinline__ float row16_sum(float x) {
  x += dppf<0x128>(x);
  x += dppf<0x124>(x);
  x += dppf<0x122>(x);
  x += dppf<0x121>(x);
  return x;
}

// ---------------------------------------------------------------------------
// f32 -> bf16 conversion (vectorized, grid-stride)
// ---------------------------------------------------------------------------
__global__ void cvt_f32_bf16(const float* __restrict__ in,
                             __hip_bfloat16* __restrict__ out, int n) {
  int i = blockIdx.x * blockDim.x + threadIdx.x;
  int stride = gridDim.x * blockDim.x;
  for (int e = i * 4; e < n; e += stride * 4) {
    float4 v = *(const float4*)(in + e);
    ushort4 u;
    u.x = f2bf_bits(v.x); u.y = f2bf_bits(v.y);
    u.z = f2bf_bits(v.z); u.w = f2bf_bits(v.w);
    *reinterpret_cast<ushort4*>(reinterpret_cast<unsigned short*>(out) + e) = u;
  }
}

// ---------------------------------------------------------------------------
// GEMM: C[M,N] = A[M,K] * B[N,K]^T   (both bf16, B^T layout)  (m97 structure)
// ---------------------------------------------------------------------------
template <bool OUT_BF16>
__global__ __launch_bounds__(256) void gemm_bt_kernel(
    const __hip_bfloat16* __restrict__ A, const __hip_bfloat16* __restrict__ B,
    void* __restrict__ Cv, int M, int N, int K) {
  __shared__ __hip_bfloat16 sA[128 * 32];
  __shared__ __hip_bfloat16 sB[128 * 32];
  const int tid = threadIdx.x;
  const int w = tid >> 6, l = tid & 63;
  const int wr = w >> 1, wc = w & 1;
  const int lr = l & 15, lk = (l >> 4) << 3;
  const int brow = blockIdx.y * 128;
  const int bcol = blockIdx.x * 128;

  f32x4 acc[4][4];
#pragma unroll
  for (int m = 0; m < 4; m++)
#pragma unroll
    for (int n = 0; n < 4; n++) acc[m][n] = (f32x4){0.f, 0.f, 0.f, 0.f};

  const int r0 = tid >> 2;
  const int c0 = (tid & 3) << 3;
  const __hip_bfloat16* Ag = A + (size_t)(brow + r0) * K + c0;
  const __hip_bfloat16* Bg = B + (size_t)(bcol + r0) * K + c0;

  for (int k0 = 0; k0 < K; k0 += 32) {
    GLOAD_LDS16(Ag + k0,                  sA + tid * 8);
    GLOAD_LDS16(Ag + k0 + (size_t)64 * K, sA + 2048 + tid * 8);
    GLOAD_LDS16(Bg + k0,                  sB + tid * 8);
    GLOAD_LDS16(Bg + k0 + (size_t)64 * K, sB + 2048 + tid * 8);
    __syncthreads();

    bf16x8 af[4], bfr[4];
#pragma unroll
    for (int m = 0; m < 4; m++)
      af[m] = *(const bf16x8*)&sA[(wr * 64 + m * 16 + lr) * 32 + lk];
#pragma unroll
    for (int n = 0; n < 4; n++)
      bfr[n] = *(const bf16x8*)&sB[(wc * 64 + n * 16 + lr) * 32 + lk];
#pragma unroll
    for (int m = 0; m < 4; m++)
#pragma unroll
      for (int n = 0; n < 4; n++)
        acc[m][n] = __builtin_amdgcn_mfma_f32_16x16x32_bf16(af[m], bfr[n],
                                                            acc[m][n], 0, 0, 0);
    __syncthreads();
  }

  const int jr = (l >> 4) << 2;
  if (OUT_BF16) {
    __hip_bfloat16* C = (__hip_bfloat16*)Cv;
#pragma unroll
    for (int m = 0; m < 4; m++)
#pragma unroll
      for (int n = 0; n < 4; n++)
#pragma unroll
        for (int j = 0; j < 4; j++) {
          size_t row = brow + wr * 64 + m * 16 + jr + j;
          size_t col = bcol + wc * 64 + n * 16 + lr;
          C[row * N + col] = __float2bfloat16(acc[m][n][j]);
        }
  } else {
    float* C = (float*)Cv;
#pragma unroll
    for (int m = 0; m < 4; m++)
#pragma unroll
      for (int n = 0; n < 4; n++)
#pragma unroll
        for (int j = 0; j < 4; j++) {
          size_t row = brow + wr * 64 + m * 16 + jr + j;
          size_t col = bcol + wc * 64 + n * 16 + lr;
          C[row * N + col] = acc[m][n][j];
        }
  }
}

// ---------------------------------------------------------------------------
// RoPE (neox) in-place on Q (heads 0..31) and K (heads 32..39) of QKV.
// ---------------------------------------------------------------------------
__global__ void rope_kernel(__hip_bfloat16* __restrict__ QKV,
                            const int* __restrict__ pos) {
  int idx = blockIdx.x * blockDim.x + threadIdx.x;  // S*40*64 total
  int d = idx & 63;
  int head = (idx >> 6) % 40;
  int s = idx / (64 * 40);
  float p = (float)pos[s];
  float inv = exp2f(-(float)d * 0.2076205059304297f);
  float fr = p * inv;
  float sn, cs;
  sincosf(fr, &sn, &cs);
  size_t base = (size_t)s * QKV_LD + head * 128 + d;
  float x1 = __bfloat162float(QKV[base]);
  float x2 = __bfloat162float(QKV[base + 64]);
  QKV[base]      = __float2bfloat16(x1 * cs - x2 * sn);
  QKV[base + 64] = __float2bfloat16(x2 * cs + x1 * sn);
}

// ---------------------------------------------------------------------------
// V transpose: Vt[kvh][d][s] = QKV[s][5120 + kvh*128 + d]
// ---------------------------------------------------------------------------
__global__ void vtrans_kernel(const __hip_bfloat16* __restrict__ QKV,
                              __hip_bfloat16* __restrict__ Vt) {
  int idx = blockIdx.x * blockDim.x + threadIdx.x;  // 8*128*2048
  int s = idx & 2047;
  int d = (idx >> 11) & 127;
  int kh = idx >> 18;
  Vt[idx] = QKV[(size_t)s * QKV_LD + 5120 + kh * 128 + d];
}

// ---------------------------------------------------------------------------
// Causal GQA flash attention, v2.
// Block = (head h, 64 q rows), 4 waves x 16 rows, KBLK=32.
// - full trips (no mask) split from the single diagonal (masked) trip
// - DPP row reductions (no shfl / ds_bpermute)
// - V fragments hoisted before softmax; no asm memory barrier
// - defer-max (THR=8 in log2 domain) skips O-rescale on stable trips
// - XCD swizzle: kvh == blockIdx % 8
// ---------------------------------------------------------------------------
__global__ __launch_bounds__(256, 4) void attn_kernel(
    const __hip_bfloat16* __restrict__ QKV,
    const __hip_bfloat16* __restrict__ Vt, __hip_bfloat16* __restrict__ O) {
  __shared__ __align__(16) __hip_bfloat16 Ps[4][16][40];  // padded rows
  const int tid = threadIdx.x;
  const int w = tid >> 6, l = tid & 63;
  const int bid = blockIdx.x;
  const int h = (bid & 7) * 4 + ((bid >> 3) & 3);  // kvh = bid & 7
  const int qt = bid >> 5;
  const int kvh = h >> 2;
  const int qb = qt * 64 + w * 16;
  const int lr = l & 15;
  const int lk = (l >> 4) << 3;
  const int jr = (l >> 4) << 2;

  const __hip_bfloat16* Qp = QKV + (size_t)h * DH;
  const __hip_bfloat16* Kp = QKV + 4096 + (size_t)kvh * DH;
  const __hip_bfloat16* Vp = Vt + (size_t)kvh * (DH * S_SEQ);

  bf16x8 qf[4];
  {
    const __hip_bfloat16* qrow = Qp + (size_t)(qb + lr) * QKV_LD + lk;
#pragma unroll
    for (int kk = 0; kk < 4; kk++) qf[kk] = *(const bf16x8*)(qrow + kk * 32);
  }

  f32x4 oacc[8];
#pragma unroll
  for (int dc = 0; dc < 8; dc++) oacc[dc] = (f32x4){0.f, 0.f, 0.f, 0.f};
  float mrun[4], lrun[4];
#pragma unroll
  for (int j = 0; j < 4; j++) { mrun[j] = -1e30f; lrun[j] = 0.f; }

#define TRIP_BODY(KB, MASKED)                                                  \
  {                                                                            \
    const int kb = (KB);                                                       \
    f32x4 sacc0 = (f32x4){0.f, 0.f, 0.f, 0.f};                                 \
    f32x4 sacc1 = (f32x4){0.f, 0.f, 0.f, 0.f};                                 \
    const __hip_bfloat16* kr0 = Kp + (size_t)(kb + lr) * QKV_LD + lk;          \
    const __hip_bfloat16* kr1 = kr0 + (size_t)16 * QKV_LD;                     \
    bf16x8 kf0[4], kf1[4];                                                     \
    _Pragma("unroll") for (int kk = 0; kk < 4; kk++) {                         \
      kf0[kk] = *(const bf16x8*)(kr0 + kk * 32);                               \
      kf1[kk] = *(const bf16x8*)(kr1 + kk * 32);                               \
    }                                                                          \
    _Pragma("unroll") for (int kk = 0; kk < 4; kk++) {                         \
      sacc0 = __builtin_amdgcn_mfma_f32_16x16x32_bf16(qf[kk], kf0[kk], sacc0,  \
                                                      0, 0, 0);                \
      sacc1 = __builtin_amdgcn_mfma_f32_16x16x32_bf16(qf[kk], kf1[kk], sacc1,  \
                                                      0, 0, 0);                \
    }                                                                          \
    bf16x8 vf[8];                                                              \
    _Pragma("unroll") for (int dc = 0; dc < 8; dc++) vf[dc] =                  \
        *(const bf16x8*)(Vp + (size_t)(dc * 16 + lr) * S_SEQ + kb + lk);       \
    float s0[4], s1[4], rm[4];                                                 \
    _Pragma("unroll") for (int j = 0; j < 4; j++) {                            \
      float a = sacc0[j] * C2F;                                                \
      float b = sacc1[j] * C2F;                                                \
      if (MASKED) {                                                            \
        const int q = qb + jr + j;                                             \
        a = (kb + lr <= q) ? a : -1e30f;                                       \
        b = (kb + 16 + lr <= q) ? b : -1e30f;                                  \
      }                                                                        \
      s0[j] = a;                                                               \
      s1[j] = b;                                                               \
      rm[j] = row16_max(fmaxf(a, b));                                          \
    }                                                                          \
    float g = fmaxf(fmaxf(rm[0] - mrun[0], rm[1] - mrun[1]),                   \
                    fmaxf(rm[2] - mrun[2], rm[3] - mrun[3]));                  \
    if (__any(g > 8.0f)) {                                                     \
      _Pragma("unroll") for (int j = 0; j < 4; j++) {                          \
        float mn = fmaxf(mrun[j], rm[j]);                                      \
        float sc = __builtin_amdgcn_exp2f(mrun[j] - mn);                       \
        lrun[j] *= sc;                                                         \
        mrun[j] = mn;                                                          \
        _Pragma("unroll") for (int dc = 0; dc < 8; dc++) oacc[dc][j] *= sc;    \
      }                                                                        \
    }                                                                          \
    _Pragma("unroll") for (int j = 0; j < 4; j++) {                            \
      float p0 = __builtin_amdgcn_exp2f(s0[j] - mrun[j]);                      \
      float p1 = __builtin_amdgcn_exp2f(s1[j] - mrun[j]);                      \
      lrun[j] += row16_sum(p0 + p1);                                           \
      Ps[w][jr + j][lr] = __float2bfloat16(p0);                                \
      Ps[w][jr + j][lr + 16] = __float2bfloat16(p1);                           \
    }                                                                          \
    bf16x8 pa = *(const bf16x8*)&Ps[w][lr][lk];                                \
    _Pragma("unroll") for (int dc = 0; dc < 8; dc++) oacc[dc] =                \
        __builtin_amdgcn_mfma_f32_16x16x32_bf16(pa, vf[dc], oacc[dc], 0, 0, 0);\
  }

  const int nfull = qb >> 5;
  for (int t = 0; t < nfull; t++) TRIP_BODY(t << 5, false);
  TRIP_BODY(nfull << 5, true);
#undef TRIP_BODY

#pragma unroll
  for (int j = 0; j < 4; j++) {
    float inv = 1.0f / lrun[j];
    const size_t rowoff = (size_t)(qb + jr + j) * (NQH * DH) + h * DH;
#pragma unroll
    for (int dc = 0; dc < 8; dc++)
      O[rowoff + dc * 16 + lr] = __float2bfloat16(oacc[dc][j] * inv);
  }
}

// ---------------------------------------------------------------------------
extern "C" void kernel_launch(void* const* d_in, const int* in_sizes, int n_in,
                              void* d_out, int out_size, void* d_ws,
                              size_t ws_size, hipStream_t stream) {
  const float* hs = (const float*)d_in[0];
  const int* pos = (const int*)d_in[1];
  const float* wqkv = (const float*)d_in[2];
  const float* wo = (const float*)d_in[3];
  float* out = (float*)d_out;

  char* ws = (char*)d_ws;
  __hip_bfloat16* Xb      = (__hip_bfloat16*)(ws);                // 16 MB
  __hip_bfloat16* Wqkvb   = (__hip_bfloat16*)(ws + 16777216);     // 48 MB
  __hip_bfloat16* Wob     = (__hip_bfloat16*)(ws + 67108864);     // 32 MB
  __hip_bfloat16* QKV     = (__hip_bfloat16*)(ws + 100663296);    // 24 MB
  __hip_bfloat16* AttnOut = (__hip_bfloat16*)(ws + 125829120);    // 16 MB
  __hip_bfloat16* Vt      = (__hip_bfloat16*)(ws + 142606336);    // 4 MB

  cvt_f32_bf16<<<2048, 256, 0, stream>>>(hs, Xb, S_SEQ * HID);
  cvt_f32_bf16<<<2048, 256, 0, stream>>>(wqkv, Wqkvb, QKV_LD * HID);
  cvt_f32_bf16<<<2048, 256, 0, stream>>>(wo, Wob, HID * HID);

  gemm_bt_kernel<true><<<dim3(QKV_LD / 128, S_SEQ / 128), 256, 0, stream>>>(
      Xb, Wqkvb, QKV, S_SEQ, QKV_LD, HID);

  rope_kernel<<<(S_SEQ * 40 * 64) / 256, 256, 0, stream>>>(QKV, pos);
  vtrans_kernel<<<(NKVH * DH * S_SEQ) / 256, 256, 0, stream>>>(QKV, Vt);

  attn_kernel<<<1024, 256, 0, stream>>>(QKV, Vt, AttnOut);

  gemm_bt_kernel<false><<<dim3(HID / 128, S_SEQ / 128), 256, 0, stream>>>(
      AttnOut, Wob, out, S_SEQ, HID, HID);
}

// Round 5
// 490.570 us; speedup vs baseline: 1.2557x; 1.2086x over previous
//
#include <hip/hip_runtime.h>
#include <hip/hip_bf16.h>
#include <cstdint>

#define S_SEQ   2048
#define HID     4096
#define NQH     32
#define NKVH    8
#define DH      128
#define QKV_LD  6144      // (32+16)*128
#define SCALE_F 0.08838834764831845f
// softmax in log2 domain: s' = s * SCALE * log2(e)
#define C2F (0.08838834764831845f * 1.4426950408889634f)

using f32x4  = __attribute__((ext_vector_type(4))) float;
using f32x16 = __attribute__((ext_vector_type(16))) float;
using bf16x8 = __attribute__((ext_vector_type(8))) __bf16;

#define GLOAD_LDS16(gp, lp)                                                   \
  __builtin_amdgcn_global_load_lds(                                           \
      (__attribute__((address_space(1))) const void*)(gp),                    \
      (__attribute__((address_space(3))) void*)(lp), 16, 0, 0)

__device__ __forceinline__ unsigned short f2bf_bits(float f) {
  __hip_bfloat16 b = __float2bfloat16(f);
  return __builtin_bit_cast(unsigned short, b);
}

// ---------------------------------------------------------------------------
// f32 -> bf16 conversion (vectorized, grid-stride)
// ---------------------------------------------------------------------------
__global__ void cvt_f32_bf16(const float* __restrict__ in,
                             __hip_bfloat16* __restrict__ out, int n) {
  int i = blockIdx.x * blockDim.x + threadIdx.x;
  int stride = gridDim.x * blockDim.x;
  for (int e = i * 4; e < n; e += stride * 4) {
    float4 v = *(const float4*)(in + e);
    ushort4 u;
    u.x = f2bf_bits(v.x); u.y = f2bf_bits(v.y);
    u.z = f2bf_bits(v.z); u.w = f2bf_bits(v.w);
    *reinterpret_cast<ushort4*>(reinterpret_cast<unsigned short*>(out) + e) = u;
  }
}

// ---------------------------------------------------------------------------
// GEMM: C[M,N] = A[M,K] * B[N,K]^T   (both bf16, B^T layout)  (m97 structure)
// ---------------------------------------------------------------------------
template <bool OUT_BF16>
__global__ __launch_bounds__(256) void gemm_bt_kernel(
    const __hip_bfloat16* __restrict__ A, const __hip_bfloat16* __restrict__ B,
    void* __restrict__ Cv, int M, int N, int K) {
  __shared__ __hip_bfloat16 sA[128 * 32];
  __shared__ __hip_bfloat16 sB[128 * 32];
  const int tid = threadIdx.x;
  const int w = tid >> 6, l = tid & 63;
  const int wr = w >> 1, wc = w & 1;
  const int lr = l & 15, lk = (l >> 4) << 3;
  const int brow = blockIdx.y * 128;
  const int bcol = blockIdx.x * 128;

  f32x4 acc[4][4];
#pragma unroll
  for (int m = 0; m < 4; m++)
#pragma unroll
    for (int n = 0; n < 4; n++) acc[m][n] = (f32x4){0.f, 0.f, 0.f, 0.f};

  const int r0 = tid >> 2;
  const int c0 = (tid & 3) << 3;
  const __hip_bfloat16* Ag = A + (size_t)(brow + r0) * K + c0;
  const __hip_bfloat16* Bg = B + (size_t)(bcol + r0) * K + c0;

  for (int k0 = 0; k0 < K; k0 += 32) {
    GLOAD_LDS16(Ag + k0,                  sA + tid * 8);
    GLOAD_LDS16(Ag + k0 + (size_t)64 * K, sA + 2048 + tid * 8);
    GLOAD_LDS16(Bg + k0,                  sB + tid * 8);
    GLOAD_LDS16(Bg + k0 + (size_t)64 * K, sB + 2048 + tid * 8);
    __syncthreads();

    bf16x8 af[4], bfr[4];
#pragma unroll
    for (int m = 0; m < 4; m++)
      af[m] = *(const bf16x8*)&sA[(wr * 64 + m * 16 + lr) * 32 + lk];
#pragma unroll
    for (int n = 0; n < 4; n++)
      bfr[n] = *(const bf16x8*)&sB[(wc * 64 + n * 16 + lr) * 32 + lk];
#pragma unroll
    for (int m = 0; m < 4; m++)
#pragma unroll
      for (int n = 0; n < 4; n++)
        acc[m][n] = __builtin_amdgcn_mfma_f32_16x16x32_bf16(af[m], bfr[n],
                                                            acc[m][n], 0, 0, 0);
    __syncthreads();
  }

  const int jr = (l >> 4) << 2;
  if (OUT_BF16) {
    __hip_bfloat16* C = (__hip_bfloat16*)Cv;
#pragma unroll
    for (int m = 0; m < 4; m++)
#pragma unroll
      for (int n = 0; n < 4; n++)
#pragma unroll
        for (int j = 0; j < 4; j++) {
          size_t row = brow + wr * 64 + m * 16 + jr + j;
          size_t col = bcol + wc * 64 + n * 16 + lr;
          C[row * N + col] = __float2bfloat16(acc[m][n][j]);
        }
  } else {
    float* C = (float*)Cv;
#pragma unroll
    for (int m = 0; m < 4; m++)
#pragma unroll
      for (int n = 0; n < 4; n++)
#pragma unroll
        for (int j = 0; j < 4; j++) {
          size_t row = brow + wr * 64 + m * 16 + jr + j;
          size_t col = bcol + wc * 64 + n * 16 + lr;
          C[row * N + col] = acc[m][n][j];
        }
  }
}

// ---------------------------------------------------------------------------
// RoPE (neox) in-place on Q (heads 0..31) and K (heads 32..39) of QKV.
// ---------------------------------------------------------------------------
__global__ void rope_kernel(__hip_bfloat16* __restrict__ QKV,
                            const int* __restrict__ pos) {
  int idx = blockIdx.x * blockDim.x + threadIdx.x;  // S*40*64 total
  int d = idx & 63;
  int head = (idx >> 6) % 40;
  int s = idx / (64 * 40);
  float p = (float)pos[s];
  float inv = exp2f(-(float)d * 0.2076205059304297f);
  float fr = p * inv;
  float sn, cs;
  sincosf(fr, &sn, &cs);
  size_t base = (size_t)s * QKV_LD + head * 128 + d;
  float x1 = __bfloat162float(QKV[base]);
  float x2 = __bfloat162float(QKV[base + 64]);
  QKV[base]      = __float2bfloat16(x1 * cs - x2 * sn);
  QKV[base + 64] = __float2bfloat16(x2 * cs + x1 * sn);
}

// ---------------------------------------------------------------------------
// V transpose: Vt[kvh][d][s] = QKV[s][5120 + kvh*128 + d]
// ---------------------------------------------------------------------------
__global__ void vtrans_kernel(const __hip_bfloat16* __restrict__ QKV,
                              __hip_bfloat16* __restrict__ Vt) {
  int idx = blockIdx.x * blockDim.x + threadIdx.x;  // 8*128*2048
  int s = idx & 2047;
  int d = (idx >> 11) & 127;
  int kh = idx >> 18;
  Vt[idx] = QKV[(size_t)s * QKV_LD + 5120 + kh * 128 + d];
}

// ---------------------------------------------------------------------------
// Causal GQA flash attention, v4: swapped-QK 32x32 + LDS P round-trip.
//
// mfma_f32_32x32x16_bf16 layouts used:
//   A-frag: lane l holds A[row = l&31][k = (l>>5)*8 + j], j=0..7
//   B-frag: lane l holds B[k = (l>>5)*8 + j][col = l&31]
//   C/D:    lane l holds D[row = (r&3)+8*(r>>2)+4*(l>>5)][col = l&31], r=0..15
//
// QK^T swapped: S[kv,q] = mfma(A=K-slice, B=Q^T-slice) -> lane owns q = l&31.
// Softmax lane-local + 1 shfl_xor(32). P goes through a per-warp LDS tile
// Ps[w][q][kv] (pairs along kv are contiguous -> 8 u32 stores), then each
// lane reads its PV B-frags as bf16x8 (same-wave ordering, no barrier; this
// is the R1/R2-verified pattern). PV: O^T[d,q] = mfma(A=V^T-slice, B=P-slice).
// Block = 4 warps = 4 q-heads of one kv-head, same 32 q-rows -> balanced.
// Grid 512 = 8 kvh (XCD swizzle) x 64 q-tiles, longest-first dispatch.
// ---------------------------------------------------------------------------
__global__ __launch_bounds__(256, 2) void attn_kernel(
    const __hip_bfloat16* __restrict__ QKV,
    const __hip_bfloat16* __restrict__ Vt, __hip_bfloat16* __restrict__ O) {
  __shared__ __align__(16) __hip_bfloat16 Ps[4][32][40];  // padded kv rows
  const int tid = threadIdx.x;
  const int w = tid >> 6, l = tid & 63;
  const int l31 = l & 31;
  const int hiP = l >> 5;
  const int bid = blockIdx.x;
  const int kvh = bid & 7;                 // XCD-resident kv head
  const int qt = 63 - (bid >> 3);          // longest blocks dispatched first
  const int h = kvh * 4 + w;               // this warp's q head
  const int qwb = qt * 32;                 // warp q base row
  const int qg = qwb + l31;                // this lane's q row

  const __hip_bfloat16* Qp = QKV + (size_t)h * DH;
  const __hip_bfloat16* Kp = QKV + 4096 + (size_t)kvh * DH;
  const __hip_bfloat16* Vp = Vt + (size_t)kvh * (DH * S_SEQ);

  // Q B-frags (held whole kernel): qf[ks] = Q[q=l31][ks*16 + hiP*8 .. +8]
  bf16x8 qf[8];
  {
    const __hip_bfloat16* qrow = Qp + (size_t)(qwb + l31) * QKV_LD + hiP * 8;
#pragma unroll
    for (int ks = 0; ks < 8; ks++) qf[ks] = *(const bf16x8*)(qrow + ks * 16);
  }

  f32x16 oacc[4];
#pragma unroll
  for (int db = 0; db < 4; db++)
#pragma unroll
    for (int r = 0; r < 16; r++) oacc[db][r] = 0.f;
  float m = -1e30f, lsum = 0.f;

#define TILE_BODY(KB, MASKED)                                                  \
  {                                                                            \
    const int kb_ = (KB);                                                      \
    /* K A-frags + V^T A-frags (independent loads, issue all up front) */      \
    bf16x8 kf[8];                                                              \
    {                                                                          \
      const __hip_bfloat16* krow =                                             \
          Kp + (size_t)(kb_ + l31) * QKV_LD + hiP * 8;                         \
      _Pragma("unroll") for (int ks = 0; ks < 8; ks++) kf[ks] =                \
          *(const bf16x8*)(krow + ks * 16);                                    \
    }                                                                          \
    bf16x8 vf[4][2];                                                           \
    _Pragma("unroll") for (int db = 0; db < 4; db++)                           \
        _Pragma("unroll") for (int k2 = 0; k2 < 2; k2++) vf[db][k2] =          \
        *(const bf16x8*)(Vp + (size_t)(db * 32 + l31) * S_SEQ + kb_ +          \
                         k2 * 16 + hiP * 8);                                   \
    f32x16 sacc;                                                               \
    _Pragma("unroll") for (int r = 0; r < 16; r++) sacc[r] = 0.f;              \
    _Pragma("unroll") for (int ks = 0; ks < 8; ks++) sacc =                    \
        __builtin_amdgcn_mfma_f32_32x32x16_bf16(kf[ks], qf[ks], sacc, 0, 0, 0);\
    float s[16];                                                               \
    _Pragma("unroll") for (int r = 0; r < 16; r++) s[r] = sacc[r] * C2F;       \
    if (MASKED) {                                                              \
      _Pragma("unroll") for (int r = 0; r < 16; r++) {                         \
        const int kvg = kb_ + (r & 3) + 8 * (r >> 2) + 4 * hiP;                \
        s[r] = (kvg <= qg) ? s[r] : -1e30f;                                    \
      }                                                                        \
    }                                                                          \
    /* row max: local tree + cross-half */                                     \
    float m0 = fmaxf(fmaxf(s[0], s[1]), fmaxf(s[2], s[3]));                    \
    float m1 = fmaxf(fmaxf(s[4], s[5]), fmaxf(s[6], s[7]));                    \
    float m2 = fmaxf(fmaxf(s[8], s[9]), fmaxf(s[10], s[11]));                  \
    float m3 = fmaxf(fmaxf(s[12], s[13]), fmaxf(s[14], s[15]));                \
    float rmax = fmaxf(fmaxf(m0, m1), fmaxf(m2, m3));                          \
    rmax = fmaxf(rmax, __shfl_xor(rmax, 32));                                  \
    if (__any(rmax - m > 8.0f)) {                                              \
      float mn = fmaxf(m, rmax);                                               \
      float sc = __builtin_amdgcn_exp2f(m - mn);                               \
      lsum *= sc;                                                              \
      _Pragma("unroll") for (int db = 0; db < 4; db++)                         \
          _Pragma("unroll") for (int r = 0; r < 16; r++) oacc[db][r] *= sc;    \
      m = mn;                                                                  \
    }                                                                          \
    float p[16];                                                               \
    _Pragma("unroll") for (int r = 0; r < 16; r++) p[r] =                      \
        __builtin_amdgcn_exp2f(s[r] - m);                                      \
    float rs = ((p[0] + p[1]) + (p[2] + p[3])) +                               \
               ((p[4] + p[5]) + (p[6] + p[7])) +                               \
               ((p[8] + p[9]) + (p[10] + p[11])) +                             \
               ((p[12] + p[13]) + (p[14] + p[15]));                            \
    lsum += rs + __shfl_xor(rs, 32);                                           \
    /* P -> per-warp LDS [q][kv]; kv pairs contiguous (r even -> crow even) */ \
    _Pragma("unroll") for (int i = 0; i < 8; i++) {                            \
      const int c_ = ((2 * i) & 3) + 8 * ((2 * i) >> 2) + 4 * hiP;             \
      unsigned pk = (unsigned)f2bf_bits(p[2 * i]) |                            \
                    ((unsigned)f2bf_bits(p[2 * i + 1]) << 16);                 \
      *(unsigned*)&Ps[w][l31][c_] = pk;                                        \
    }                                                                          \
    bf16x8 pfrag[2];                                                           \
    _Pragma("unroll") for (int k2 = 0; k2 < 2; k2++) pfrag[k2] =               \
        *(const bf16x8*)&Ps[w][l31][k2 * 16 + hiP * 8];                        \
    _Pragma("unroll") for (int db = 0; db < 4; db++)                           \
        _Pragma("unroll") for (int k2 = 0; k2 < 2; k2++) oacc[db] =            \
        __builtin_amdgcn_mfma_f32_32x32x16_bf16(vf[db][k2], pfrag[k2],         \
                                                oacc[db], 0, 0, 0);            \
  }

  for (int kb = 0; kb < qwb; kb += 32) TILE_BODY(kb, false);
  TILE_BODY(qwb, true);
#undef TILE_BODY

  // write O[q][h*128 + d], d = db*32 + 8*(r>>2) + 4*hiP + (r&3)
  const float inv = 1.0f / lsum;
  __hip_bfloat16* orow = O + (size_t)qg * (NQH * DH) + h * DH;
#pragma unroll
  for (int db = 0; db < 4; db++)
#pragma unroll
    for (int rg = 0; rg < 4; rg++) {
      ushort4 u;
      u.x = f2bf_bits(oacc[db][rg * 4 + 0] * inv);
      u.y = f2bf_bits(oacc[db][rg * 4 + 1] * inv);
      u.z = f2bf_bits(oacc[db][rg * 4 + 2] * inv);
      u.w = f2bf_bits(oacc[db][rg * 4 + 3] * inv);
      *reinterpret_cast<ushort4*>(orow + db * 32 + 8 * rg + 4 * hiP) = u;
    }
}

// ---------------------------------------------------------------------------
extern "C" void kernel_launch(void* const* d_in, const int* in_sizes, int n_in,
                              void* d_out, int out_size, void* d_ws,
                              size_t ws_size, hipStream_t stream) {
  const float* hs = (const float*)d_in[0];
  const int* pos = (const int*)d_in[1];
  const float* wqkv = (const float*)d_in[2];
  const float* wo = (const float*)d_in[3];
  float* out = (float*)d_out;

  char* ws = (char*)d_ws;
  __hip_bfloat16* Xb      = (__hip_bfloat16*)(ws);                // 16 MB
  __hip_bfloat16* Wqkvb   = (__hip_bfloat16*)(ws + 16777216);     // 48 MB
  __hip_bfloat16* Wob     = (__hip_bfloat16*)(ws + 67108864);     // 32 MB
  __hip_bfloat16* QKV     = (__hip_bfloat16*)(ws + 100663296);    // 24 MB
  __hip_bfloat16* AttnOut = (__hip_bfloat16*)(ws + 125829120);    // 16 MB
  __hip_bfloat16* Vt      = (__hip_bfloat16*)(ws + 142606336);    // 4 MB

  cvt_f32_bf16<<<2048, 256, 0, stream>>>(hs, Xb, S_SEQ * HID);
  cvt_f32_bf16<<<2048, 256, 0, stream>>>(wqkv, Wqkvb, QKV_LD * HID);
  cvt_f32_bf16<<<2048, 256, 0, stream>>>(wo, Wob, HID * HID);

  gemm_bt_kernel<true><<<dim3(QKV_LD / 128, S_SEQ / 128), 256, 0, stream>>>(
      Xb, Wqkvb, QKV, S_SEQ, QKV_LD, HID);

  rope_kernel<<<(S_SEQ * 40 * 64) / 256, 256, 0, stream>>>(QKV, pos);
  vtrans_kernel<<<(NKVH * DH * S_SEQ) / 256, 256, 0, stream>>>(QKV, Vt);

  attn_kernel<<<512, 256, 0, stream>>>(QKV, Vt, AttnOut);

  gemm_bt_kernel<false><<<dim3(HID / 128, S_SEQ / 128), 256, 0, stream>>>(
      AttnOut, Wob, out, S_SEQ, HID, HID);
}

// Round 6
// 489.621 us; speedup vs baseline: 1.2581x; 1.0019x over previous
//
#include <hip/hip_runtime.h>
#include <hip/hip_bf16.h>
#include <cstdint>

#define S_SEQ   2048
#define HID     4096
#define NQH     32
#define NKVH    8
#define DH      128
#define QKV_LD  6144      // (32+16)*128
#define SCALE_F 0.08838834764831845f
// softmax in log2 domain: s' = s * SCALE * log2(e)
#define C2F (0.08838834764831845f * 1.4426950408889634f)

using f32x4  = __attribute__((ext_vector_type(4))) float;
using f32x16 = __attribute__((ext_vector_type(16))) float;
using bf16x8 = __attribute__((ext_vector_type(8))) __bf16;
using u32x2  = __attribute__((ext_vector_type(2))) unsigned;

#define GLOAD_LDS16(gp, lp)                                                   \
  __builtin_amdgcn_global_load_lds(                                           \
      (__attribute__((address_space(1))) const void*)(gp),                    \
      (__attribute__((address_space(3))) void*)(lp), 16, 0, 0)

__device__ __forceinline__ unsigned short f2bf_bits(float f) {
  __hip_bfloat16 b = __float2bfloat16(f);
  return __builtin_bit_cast(unsigned short, b);
}

// permlane32_swap: X[32..63] <-> Y[0..31].
// lo lane: X'=own X, Y'=partner's X.  hi lane: X'=partner's Y, Y'=own Y.
__device__ __forceinline__ void plswap(unsigned& x, unsigned& y) {
  u32x2 r = __builtin_amdgcn_permlane32_swap(x, y, false, false);
  x = r[0];
  y = r[1];
}
// value of the partner lane (l ^ 32)
__device__ __forceinline__ float xhalf(float v, int hiP) {
  unsigned u = __builtin_bit_cast(unsigned, v);
  u32x2 r = __builtin_amdgcn_permlane32_swap(u, u, false, false);
  return __builtin_bit_cast(float, hiP ? r[0] : r[1]);
}

// ---------------------------------------------------------------------------
// f32 -> bf16 conversion (vectorized, grid-stride)
// ---------------------------------------------------------------------------
__global__ void cvt_f32_bf16(const float* __restrict__ in,
                             __hip_bfloat16* __restrict__ out, int n) {
  int i = blockIdx.x * blockDim.x + threadIdx.x;
  int stride = gridDim.x * blockDim.x;
  for (int e = i * 4; e < n; e += stride * 4) {
    float4 v = *(const float4*)(in + e);
    ushort4 u;
    u.x = f2bf_bits(v.x); u.y = f2bf_bits(v.y);
    u.z = f2bf_bits(v.z); u.w = f2bf_bits(v.w);
    *reinterpret_cast<ushort4*>(reinterpret_cast<unsigned short*>(out) + e) = u;
  }
}

// ---------------------------------------------------------------------------
// GEMM: C[M,N] = A[M,K] * B[N,K]^T   (both bf16, B^T layout)  (m97 structure)
// + bijective XCD swizzle on the flattened block id (grids are %8 == 0).
// ---------------------------------------------------------------------------
template <bool OUT_BF16>
__global__ __launch_bounds__(256) void gemm_bt_kernel(
    const __hip_bfloat16* __restrict__ A, const __hip_bfloat16* __restrict__ B,
    void* __restrict__ Cv, int M, int N, int K) {
  __shared__ __hip_bfloat16 sA[128 * 32];
  __shared__ __hip_bfloat16 sB[128 * 32];
  const int tid = threadIdx.x;
  const int w = tid >> 6, l = tid & 63;
  const int wr = w >> 1, wc = w & 1;
  const int lr = l & 15, lk = (l >> 4) << 3;

  const int nbx = gridDim.x;
  const int nwg = nbx * gridDim.y;
  int wgid = blockIdx.y * nbx + blockIdx.x;
  wgid = (wgid & 7) * (nwg >> 3) + (wgid >> 3);  // XCD chunking
  const int brow = (wgid / nbx) * 128;
  const int bcol = (wgid % nbx) * 128;

  f32x4 acc[4][4];
#pragma unroll
  for (int m = 0; m < 4; m++)
#pragma unroll
    for (int n = 0; n < 4; n++) acc[m][n] = (f32x4){0.f, 0.f, 0.f, 0.f};

  const int r0 = tid >> 2;
  const int c0 = (tid & 3) << 3;
  const __hip_bfloat16* Ag = A + (size_t)(brow + r0) * K + c0;
  const __hip_bfloat16* Bg = B + (size_t)(bcol + r0) * K + c0;

  for (int k0 = 0; k0 < K; k0 += 32) {
    GLOAD_LDS16(Ag + k0,                  sA + tid * 8);
    GLOAD_LDS16(Ag + k0 + (size_t)64 * K, sA + 2048 + tid * 8);
    GLOAD_LDS16(Bg + k0,                  sB + tid * 8);
    GLOAD_LDS16(Bg + k0 + (size_t)64 * K, sB + 2048 + tid * 8);
    __syncthreads();

    bf16x8 af[4], bfr[4];
#pragma unroll
    for (int m = 0; m < 4; m++)
      af[m] = *(const bf16x8*)&sA[(wr * 64 + m * 16 + lr) * 32 + lk];
#pragma unroll
    for (int n = 0; n < 4; n++)
      bfr[n] = *(const bf16x8*)&sB[(wc * 64 + n * 16 + lr) * 32 + lk];
#pragma unroll
    for (int m = 0; m < 4; m++)
#pragma unroll
      for (int n = 0; n < 4; n++)
        acc[m][n] = __builtin_amdgcn_mfma_f32_16x16x32_bf16(af[m], bfr[n],
                                                            acc[m][n], 0, 0, 0);
    __syncthreads();
  }

  const int jr = (l >> 4) << 2;
  if (OUT_BF16) {
    __hip_bfloat16* C = (__hip_bfloat16*)Cv;
#pragma unroll
    for (int m = 0; m < 4; m++)
#pragma unroll
      for (int n = 0; n < 4; n++)
#pragma unroll
        for (int j = 0; j < 4; j++) {
          size_t row = brow + wr * 64 + m * 16 + jr + j;
          size_t col = bcol + wc * 64 + n * 16 + lr;
          C[row * N + col] = __float2bfloat16(acc[m][n][j]);
        }
  } else {
    float* C = (float*)Cv;
#pragma unroll
    for (int m = 0; m < 4; m++)
#pragma unroll
      for (int n = 0; n < 4; n++)
#pragma unroll
        for (int j = 0; j < 4; j++) {
          size_t row = brow + wr * 64 + m * 16 + jr + j;
          size_t col = bcol + wc * 64 + n * 16 + lr;
          C[row * N + col] = acc[m][n][j];
        }
  }
}

// ---------------------------------------------------------------------------
// RoPE (neox) in-place on Q (heads 0..31) and K (heads 32..39) of QKV.
// ---------------------------------------------------------------------------
__global__ void rope_kernel(__hip_bfloat16* __restrict__ QKV,
                            const int* __restrict__ pos) {
  int idx = blockIdx.x * blockDim.x + threadIdx.x;  // S*40*64 total
  int d = idx & 63;
  int head = (idx >> 6) % 40;
  int s = idx / (64 * 40);
  float p = (float)pos[s];
  float inv = exp2f(-(float)d * 0.2076205059304297f);
  float fr = p * inv;
  float sn, cs;
  sincosf(fr, &sn, &cs);
  size_t base = (size_t)s * QKV_LD + head * 128 + d;
  float x1 = __bfloat162float(QKV[base]);
  float x2 = __bfloat162float(QKV[base + 64]);
  QKV[base]      = __float2bfloat16(x1 * cs - x2 * sn);
  QKV[base + 64] = __float2bfloat16(x2 * cs + x1 * sn);
}

// ---------------------------------------------------------------------------
// V transpose: Vt[kvh][d][s] = QKV[s][5120 + kvh*128 + d]
// ---------------------------------------------------------------------------
__global__ void vtrans_kernel(const __hip_bfloat16* __restrict__ QKV,
                              __hip_bfloat16* __restrict__ Vt) {
  int idx = blockIdx.x * blockDim.x + threadIdx.x;  // 8*128*2048
  int s = idx & 2047;
  int d = (idx >> 11) & 127;
  int kh = idx >> 18;
  Vt[idx] = QKV[(size_t)s * QKV_LD + 5120 + kh * 128 + d];
}

// ---------------------------------------------------------------------------
// Causal GQA flash attention, v5: swapped-QK 32x32, zero-LDS
// (permlane32_swap P-exchange) + 2-deep K/V register prefetch.
//
// mfma_f32_32x32x16_bf16 layouts:
//   A-frag: lane l holds A[row = l&31][k = (l>>5)*8 + j], j=0..7
//   B-frag: lane l holds B[k = (l>>5)*8 + j][col = l&31]
//   C/D:    lane l holds D[row = (r&3)+8*(r>>2)+4*(l>>5)][col = l&31], r=0..15
//
// P-exchange derivation (verified vs the passing LDS version):
//   Wp[i] = bf16pair(p[2i], p[2i+1]) covers kv pair c(2i) = (2i&3)+8*(2i>>2)+4*hiP.
//   swap(Wp0,Wp2), swap(Wp1,Wp3) -> frag k2=0 words {s0.x, s1.x, s0.y, s1.y}
//   (same positions for both half-waves); Wp4..7 likewise for k2=1.
// ---------------------------------------------------------------------------
__global__ __launch_bounds__(256, 2) void attn_kernel(
    const __hip_bfloat16* __restrict__ QKV,
    const __hip_bfloat16* __restrict__ Vt, __hip_bfloat16* __restrict__ O) {
  const int tid = threadIdx.x;
  const int w = tid >> 6, l = tid & 63;
  const int l31 = l & 31;
  const int hiP = l >> 5;
  const int bid = blockIdx.x;
  const int kvh = bid & 7;                 // XCD-resident kv head
  const int qt = 63 - (bid >> 3);          // longest blocks dispatched first
  const int h = kvh * 4 + w;               // this warp's q head
  const int qwb = qt * 32;                 // warp q base row
  const int qg = qwb + l31;                // this lane's q row

  const __hip_bfloat16* Qp = QKV + (size_t)h * DH;
  const __hip_bfloat16* Kp = QKV + 4096 + (size_t)kvh * DH;
  const __hip_bfloat16* Vp = Vt + (size_t)kvh * (DH * S_SEQ);

  // Q B-frags (held whole kernel): qf[ks] = Q[q=l31][ks*16 + hiP*8 .. +8]
  bf16x8 qf[8];
  {
    const __hip_bfloat16* qrow = Qp + (size_t)(qwb + l31) * QKV_LD + hiP * 8;
#pragma unroll
    for (int ks = 0; ks < 8; ks++) qf[ks] = *(const bf16x8*)(qrow + ks * 16);
  }

  f32x16 oacc[4];
#pragma unroll
  for (int db = 0; db < 4; db++)
#pragma unroll
    for (int r = 0; r < 16; r++) oacc[db][r] = 0.f;
  float m = -1e30f, lsum = 0.f;

#define LOAD_KV(KF, VF, KB)                                                    \
  {                                                                            \
    const int lb_ = (KB);                                                      \
    const __hip_bfloat16* krow = Kp + (size_t)(lb_ + l31) * QKV_LD + hiP * 8;  \
    _Pragma("unroll") for (int ks = 0; ks < 8; ks++) KF[ks] =                  \
        *(const bf16x8*)(krow + ks * 16);                                      \
    _Pragma("unroll") for (int db = 0; db < 4; db++)                           \
        _Pragma("unroll") for (int k2 = 0; k2 < 2; k2++) VF[db][k2] =          \
        *(const bf16x8*)(Vp + (size_t)(db * 32 + l31) * S_SEQ + lb_ +          \
                         k2 * 16 + hiP * 8);                                   \
  }

#define COMPUTE_TILE(KF, VF, KB, MASKED)                                       \
  {                                                                            \
    const int kb_ = (KB);                                                      \
    f32x16 sacc;                                                               \
    _Pragma("unroll") for (int r = 0; r < 16; r++) sacc[r] = 0.f;              \
    _Pragma("unroll") for (int ks = 0; ks < 8; ks++) sacc =                    \
        __builtin_amdgcn_mfma_f32_32x32x16_bf16(KF[ks], qf[ks], sacc, 0, 0, 0);\
    float s[16];                                                               \
    _Pragma("unroll") for (int r = 0; r < 16; r++) s[r] = sacc[r] * C2F;       \
    if (MASKED) {                                                              \
      _Pragma("unroll") for (int r = 0; r < 16; r++) {                         \
        const int kvg = kb_ + (r & 3) + 8 * (r >> 2) + 4 * hiP;                \
        s[r] = (kvg <= qg) ? s[r] : -1e30f;                                    \
      }                                                                        \
    }                                                                          \
    float m0 = fmaxf(fmaxf(s[0], s[1]), fmaxf(s[2], s[3]));                    \
    float m1 = fmaxf(fmaxf(s[4], s[5]), fmaxf(s[6], s[7]));                    \
    float m2 = fmaxf(fmaxf(s[8], s[9]), fmaxf(s[10], s[11]));                  \
    float m3 = fmaxf(fmaxf(s[12], s[13]), fmaxf(s[14], s[15]));                \
    float rmax = fmaxf(fmaxf(m0, m1), fmaxf(m2, m3));                          \
    rmax = fmaxf(rmax, xhalf(rmax, hiP));                                      \
    if (__any(rmax - m > 8.0f)) {                                              \
      float mn = fmaxf(m, rmax);                                               \
      float sc = __builtin_amdgcn_exp2f(m - mn);                               \
      lsum *= sc;                                                              \
      _Pragma("unroll") for (int db = 0; db < 4; db++)                         \
          _Pragma("unroll") for (int r = 0; r < 16; r++) oacc[db][r] *= sc;    \
      m = mn;                                                                  \
    }                                                                          \
    float p[16];                                                               \
    _Pragma("unroll") for (int r = 0; r < 16; r++) p[r] =                      \
        __builtin_amdgcn_exp2f(s[r] - m);                                      \
    float rs = ((p[0] + p[1]) + (p[2] + p[3])) +                               \
               ((p[4] + p[5]) + (p[6] + p[7])) +                               \
               ((p[8] + p[9]) + (p[10] + p[11])) +                             \
               ((p[12] + p[13]) + (p[14] + p[15]));                            \
    lsum += rs + xhalf(rs, hiP);                                               \
    unsigned Wp[8];                                                            \
    _Pragma("unroll") for (int i = 0; i < 8; i++) Wp[i] =                      \
        (unsigned)f2bf_bits(p[2 * i]) |                                        \
        ((unsigned)f2bf_bits(p[2 * i + 1]) << 16);                             \
    unsigned s0x = Wp[0], s0y = Wp[2];                                         \
    unsigned s1x = Wp[1], s1y = Wp[3];                                         \
    unsigned s2x = Wp[4], s2y = Wp[6];                                         \
    unsigned s3x = Wp[5], s3y = Wp[7];                                         \
    plswap(s0x, s0y);                                                          \
    plswap(s1x, s1y);                                                          \
    plswap(s2x, s2y);                                                          \
    plswap(s3x, s3y);                                                          \
    int4 f0, f1;                                                               \
    f0.x = (int)s0x; f0.y = (int)s1x; f0.z = (int)s0y; f0.w = (int)s1y;        \
    f1.x = (int)s2x; f1.y = (int)s3x; f1.z = (int)s2y; f1.w = (int)s3y;        \
    bf16x8 pfrag[2];                                                           \
    pfrag[0] = __builtin_bit_cast(bf16x8, f0);                                 \
    pfrag[1] = __builtin_bit_cast(bf16x8, f1);                                 \
    _Pragma("unroll") for (int db = 0; db < 4; db++)                           \
        _Pragma("unroll") for (int k2 = 0; k2 < 2; k2++) oacc[db] =            \
        __builtin_amdgcn_mfma_f32_32x32x16_bf16(VF[db][k2], pfrag[k2],         \
                                                oacc[db], 0, 0, 0);            \
  }

  bf16x8 kA[8], kB[8];
  bf16x8 vA[4][2], vB[4][2];
  LOAD_KV(kA, vA, 0);
  int kb = 0;
  for (; kb + 64 <= qwb; kb += 64) {
    LOAD_KV(kB, vB, kb + 32);
    COMPUTE_TILE(kA, vA, kb, false);
    LOAD_KV(kA, vA, kb + 64);
    COMPUTE_TILE(kB, vB, kb + 32, false);
  }
  if (kb < qwb) {
    LOAD_KV(kB, vB, qwb);
    COMPUTE_TILE(kA, vA, kb, false);
    COMPUTE_TILE(kB, vB, qwb, true);
  } else {
    COMPUTE_TILE(kA, vA, qwb, true);
  }
#undef LOAD_KV
#undef COMPUTE_TILE

  // write O[q][h*128 + d], d = db*32 + 8*(r>>2) + 4*hiP + (r&3)
  const float inv = 1.0f / lsum;
  __hip_bfloat16* orow = O + (size_t)qg * (NQH * DH) + h * DH;
#pragma unroll
  for (int db = 0; db < 4; db++)
#pragma unroll
    for (int rg = 0; rg < 4; rg++) {
      ushort4 u;
      u.x = f2bf_bits(oacc[db][rg * 4 + 0] * inv);
      u.y = f2bf_bits(oacc[db][rg * 4 + 1] * inv);
      u.z = f2bf_bits(oacc[db][rg * 4 + 2] * inv);
      u.w = f2bf_bits(oacc[db][rg * 4 + 3] * inv);
      *reinterpret_cast<ushort4*>(orow + db * 32 + 8 * rg + 4 * hiP) = u;
    }
}

// ---------------------------------------------------------------------------
extern "C" void kernel_launch(void* const* d_in, const int* in_sizes, int n_in,
                              void* d_out, int out_size, void* d_ws,
                              size_t ws_size, hipStream_t stream) {
  const float* hs = (const float*)d_in[0];
  const int* pos = (const int*)d_in[1];
  const float* wqkv = (const float*)d_in[2];
  const float* wo = (const float*)d_in[3];
  float* out = (float*)d_out;

  char* ws = (char*)d_ws;
  __hip_bfloat16* Xb      = (__hip_bfloat16*)(ws);                // 16 MB
  __hip_bfloat16* Wqkvb   = (__hip_bfloat16*)(ws + 16777216);     // 48 MB
  __hip_bfloat16* Wob     = (__hip_bfloat16*)(ws + 67108864);     // 32 MB
  __hip_bfloat16* QKV     = (__hip_bfloat16*)(ws + 100663296);    // 24 MB
  __hip_bfloat16* AttnOut = (__hip_bfloat16*)(ws + 125829120);    // 16 MB
  __hip_bfloat16* Vt      = (__hip_bfloat16*)(ws + 142606336);    // 4 MB

  cvt_f32_bf16<<<2048, 256, 0, stream>>>(hs, Xb, S_SEQ * HID);
  cvt_f32_bf16<<<2048, 256, 0, stream>>>(wqkv, Wqkvb, QKV_LD * HID);
  cvt_f32_bf16<<<2048, 256, 0, stream>>>(wo, Wob, HID * HID);

  gemm_bt_kernel<true><<<dim3(QKV_LD / 128, S_SEQ / 128), 256, 0, stream>>>(
      Xb, Wqkvb, QKV, S_SEQ, QKV_LD, HID);

  rope_kernel<<<(S_SEQ * 40 * 64) / 256, 256, 0, stream>>>(QKV, pos);
  vtrans_kernel<<<(NKVH * DH * S_SEQ) / 256, 256, 0, stream>>>(QKV, Vt);

  attn_kernel<<<512, 256, 0, stream>>>(QKV, Vt, AttnOut);

  gemm_bt_kernel<false><<<dim3(HID / 128, S_SEQ / 128), 256, 0, stream>>>(
      AttnOut, Wob, out, S_SEQ, HID, HID);
}